// Round 16
// baseline (88.715 us; speedup 1.0000x reference)
//
#include <hip/hip_runtime.h>

#define P 7
#define NCH 256
#define NPP 49
#define LDS_CAP 2368   // provable max Hr*(Wp+1) = 2313 (level-0, Wr=130 -> Wp=256, Hr<=9)

__global__ __launch_bounds__(256) void pooler_kernel(
    const float* __restrict__ boxes,
    const int* __restrict__ batch_ids,
    const float* __restrict__ g0, const float* __restrict__ g1,
    const float* __restrict__ g2, const float* __restrict__ g3,
    float* __restrict__ out)
{
    __shared__ float sreg[4][LDS_CAP];   // 37.9 KB; sreg[wy] is WAVE-PRIVATE

    const int n    = blockIdx.y;          // box
    const int cg   = blockIdx.x;          // channel group 0..63
    const int lane = threadIdx.x;         // 0..63
    const int wy   = threadIdx.y;         // wave index = channel within group
    const int c    = (cg << 2) | wy;

    // ---- box + level (uniform within block) ----
    const float x1i = boxes[n*4+0], y1i = boxes[n*4+1];
    const float x2i = boxes[n*4+2], y2i = boxes[n*4+3];
    const float area = (x2i - x1i) * (y2i - y1i);
    float lvlf = floorf(4.0f + log2f(sqrtf(area) / 224.0f + 1e-6f));
    lvlf = fminf(fmaxf(lvlf, 2.0f), 5.0f);
    const int lvl = (int)lvlf - 2;        // 0..3

    const float* feat = (lvl==0) ? g0 : (lvl==1) ? g1 : (lvl==2) ? g2 : g3;
    const int    L    = (lvl==0) ? 200 : (lvl==1) ? 100 : (lvl==2) ? 50 : 25;
    const float scale = (lvl==0) ? 0.25f : (lvl==1) ? 0.125f
                      : (lvl==2) ? 0.0625f : 0.03125f;
    const int b = batch_ids[n];

    const float x1 = x1i * scale, y1 = y1i * scale;
    const float bw = fmaxf(x2i*scale - x1, 1.0f) * (1.0f/7.0f);
    const float bh = fmaxf(y2i*scale - y1, 1.0f) * (1.0f/7.0f);
    const float Lf = (float)L, Lm1 = Lf - 1.0f;
    const int   Lm2 = L - 2;

    // ---- region bounds (monotone prep over samples g in [0.25, 6.75]) ----
    const int rx0 = min((int)fminf(fmaxf(x1 + 0.25f*bw, 0.0f), Lm1), Lm2);
    const int rx1 = min((int)fminf(fmaxf(x1 + 6.75f*bw, 0.0f), Lm1), Lm2);
    const int ry0 = min((int)fminf(fmaxf(y1 + 0.25f*bh, 0.0f), Lm1), Lm2);
    const int ry1 = min((int)fminf(fmaxf(y1 + 6.75f*bh, 0.0f), Lm1), Lm2);
    const int Wr = rx1 - rx0 + 2;         // region cols incl. +1 tap column (>=2)
    const int Hr = ry1 - ry0 + 2;         // region rows incl. +1 tap row

    // ---- pow2-padded layout: no div/rcp in staging ----
    const int k      = 32 - __clz(Wr - 1);   // Wp = 2^k >= Wr (Wr>=2 -> k>=1)
    const int Wp     = 1 << k;
    const int m      = Wp - 1;
    const int stride = Wp + 1;               // odd -> bank-spread on reads
    const int T2     = Hr << k;              // padded element count
    const int Hm1    = Hr - 1, Wm1 = Wr - 1;

    const float* gpr = feat + ((size_t)b * NCH + c) * (size_t)(L * L)
                     + (size_t)ry0 * L + rx0;
    float* sp = sreg[wy];

    // ---- stage region -> LDS: ~8 VALU per 256 elements, 4 loads in flight ----
    for (int f0 = lane; f0 < T2; f0 += 256) {
        int rowA[4], ldsA[4], glbA[4]; float vA[4];
#pragma unroll
        for (int j = 0; j < 4; ++j) {
            const int f   = f0 + (j << 6);
            const int row = f >> k;
            const int col = f & m;
            const int rc  = min(row, Hm1);   // clamp -> load always in-plane
            const int cc  = min(col, Wm1);   // clamp -> no extra lines fetched
            rowA[j] = row;
            glbA[j] = rc * L + cc;
            ldsA[j] = f + row;               // row*(Wp+1)+col
        }
#pragma unroll
        for (int j = 0; j < 4; ++j) vA[j] = gpr[glbA[j]];  // independent loads
#pragma unroll
        for (int j = 0; j < 4; ++j) if (rowA[j] < Hr) sp[ldsA[j]] = vA[j];
    }
    // NO __syncthreads(): sreg[wy] written and read only by wave wy (r15-proven);
    // compiler-inserted vmcnt/lgkmcnt orders load -> ds_write -> ds_read.

    // ---- bilinear interpolation from LDS (lanes 0..48 = bins) ----
    if (lane < NPP) {
        const int py = lane / P;
        const int px = lane - py * P;

        int   y0[2], x0[2];
        float fy[2], hy[2], vy[2], fx[2], hx[2], vx[2];
#pragma unroll
        for (int s = 0; s < 2; ++s) {
            const float yc = y1 + ((float)py + (s ? 0.75f : 0.25f)) * bh;
            vy[s] = (yc > -1.0f && yc < Lf) ? 1.0f : 0.0f;
            const float ycc = fminf(fmaxf(yc, 0.0f), Lm1);
            y0[s] = min((int)ycc, Lm2);
            fy[s] = ycc - (float)y0[s];
            hy[s] = 1.0f - fy[s];

            const float xc = x1 + ((float)px + (s ? 0.75f : 0.25f)) * bw;
            vx[s] = (xc > -1.0f && xc < Lf) ? 1.0f : 0.0f;
            const float xcc = fminf(fmaxf(xc, 0.0f), Lm1);
            x0[s] = min((int)xcc, Lm2);
            fx[s] = xcc - (float)x0[s];
            hx[s] = 1.0f - fx[s];
        }

        float acc = 0.0f;
#pragma unroll
        for (int sy = 0; sy < 2; ++sy) {
            const int rowa = (y0[sy] - ry0) * stride - rx0;
#pragma unroll
            for (int sx = 0; sx < 2; ++sx) {
                const int a = rowa + x0[sx];
                const float v00 = sp[a];
                const float v01 = sp[a + 1];
                const float v10 = sp[a + stride];
                const float v11 = sp[a + stride + 1];
                acc += (vy[sy] * vx[sx])
                     * (hy[sy] * (hx[sx] * v00 + fx[sx] * v01)
                      + fy[sy] * (hx[sx] * v10 + fx[sx] * v11));
            }
        }
        out[((size_t)n * NCH + c) * NPP + lane] = acc * 0.25f;
    }
}

extern "C" void kernel_launch(void* const* d_in, const int* in_sizes, int n_in,
                              void* d_out, int out_size, void* d_ws, size_t ws_size,
                              hipStream_t stream) {
    const float* boxes     = (const float*)d_in[0];
    const int*   batch_ids = (const int*)d_in[1];
    const float* g0        = (const float*)d_in[2];
    const float* g1        = (const float*)d_in[3];
    const float* g2        = (const float*)d_in[4];
    const float* g3        = (const float*)d_in[5];
    float* out = (float*)d_out;

    const int N = in_sizes[0] / 4;                 // 512
    dim3 block(64, 4);                             // 4 waves = 4 channels
    dim3 grid(NCH / 4, N);                         // (64, 512)
    pooler_kernel<<<grid, block, 0, stream>>>(boxes, batch_ids, g0, g1, g2, g3, out);
}

// Round 17
// 66.275 us; speedup vs baseline: 1.3386x; 1.3386x over previous
//
#include <hip/hip_runtime.h>

#define P 7
#define NCH 256
#define NPP 49
#define CHUNK 16    // channels per wave; 16 chunks of 16 = 256 channels

typedef float f2 __attribute__((ext_vector_type(2), aligned(4)));

__global__ __launch_bounds__(256) void pooler_kernel(
    const float* __restrict__ boxes,
    const int* __restrict__ batch_ids,
    const float* __restrict__ g0, const float* __restrict__ g1,
    const float* __restrict__ g2, const float* __restrict__ g3,
    float* __restrict__ out)
{
    const int n     = blockIdx.x;              // box 0..511
    const int wv    = threadIdx.y;             // wave 0..3
    const int chunk = blockIdx.y * 4 + wv;     // 0..15
    const int c0    = chunk * CHUNK;           // first channel of this wave
    const int lane  = threadIdx.x;             // 0..63
    const int bin   = min(lane, NPP - 1);      // lanes 49..63 mirror bin 48
    const int py    = bin / P;
    const int px    = bin - py * P;

    // ---- box + level (uniform within wave; computed once) ----
    const float x1i = boxes[n*4+0], y1i = boxes[n*4+1];
    const float x2i = boxes[n*4+2], y2i = boxes[n*4+3];
    const float area = (x2i - x1i) * (y2i - y1i);
    float lvlf = floorf(4.0f + log2f(sqrtf(area) / 224.0f + 1e-6f));
    lvlf = fminf(fmaxf(lvlf, 2.0f), 5.0f);
    const int lvl = (int)lvlf - 2;             // 0..3

    const float* feat = (lvl==0) ? g0 : (lvl==1) ? g1 : (lvl==2) ? g2 : g3;
    const int    L    = (lvl==0) ? 200 : (lvl==1) ? 100 : (lvl==2) ? 50 : 25;
    const float scale = (lvl==0) ? 0.25f : (lvl==1) ? 0.125f
                      : (lvl==2) ? 0.0625f : 0.03125f;
    const int b  = batch_ids[n];
    const int LL = L * L;

    const float x1 = x1i * scale, y1 = y1i * scale;
    const float bw = fmaxf(x2i*scale - x1, 1.0f) * (1.0f/7.0f);
    const float bh = fmaxf(y2i*scale - y1, 1.0f) * (1.0f/7.0f);
    const float Lf = (float)L, Lm1 = Lf - 1.0f;
    const int   Lm2 = L - 2;

    // ---- per-lane prep: ONCE for all 16 channels ----
    int   y0[2], x0[2];
    float fy[2], hy[2], vy[2], fx[2], hx[2], vx[2];
#pragma unroll
    for (int s = 0; s < 2; ++s) {
        const float yc = y1 + ((float)py + (s ? 0.75f : 0.25f)) * bh;
        vy[s] = (yc > -1.0f && yc < Lf) ? 1.0f : 0.0f;
        const float ycc = fminf(fmaxf(yc, 0.0f), Lm1);
        y0[s] = min((int)ycc, Lm2);
        fy[s] = ycc - (float)y0[s];
        hy[s] = 1.0f - fy[s];

        const float xc = x1 + ((float)px + (s ? 0.75f : 0.25f)) * bw;
        vx[s] = (xc > -1.0f && xc < Lf) ? 1.0f : 0.0f;
        const float xcc = fminf(fmaxf(xc, 0.0f), Lm1);
        x0[s] = min((int)xcc, Lm2);
        fx[s] = xcc - (float)x0[s];
        hx[s] = 1.0f - fx[s];
    }

    // weights pre-folded with validity mask and the x0.25 average
    float w00[2][2], w01[2][2], w10[2][2], w11[2][2];
    int   offT[2][2], offB[2][2];
#pragma unroll
    for (int sy = 0; sy < 2; ++sy)
#pragma unroll
    for (int sx = 0; sx < 2; ++sx) {
        const float w = 0.25f * vy[sy] * vx[sx];
        w00[sy][sx] = w * hy[sy] * hx[sx];
        w01[sy][sx] = w * hy[sy] * fx[sx];
        w10[sy][sx] = w * fy[sy] * hx[sx];
        w11[sy][sx] = w * fy[sy] * fx[sx];
        offT[sy][sx] = y0[sy] * L + x0[sx];
        offB[sy][sx] = offT[sy][sx] + L;
    }

    // ---- channel loop: 8 loads + 16 fmac + 1 coalesced store per channel ----
    const float* plane = feat + ((size_t)b * NCH + c0) * (size_t)LL;
    size_t ob = ((size_t)n * NCH + c0) * NPP + bin;

    for (int i = 0; i < CHUNK; ++i) {
        f2 aT[2][2], aB[2][2];
#pragma unroll
        for (int sy = 0; sy < 2; ++sy)
#pragma unroll
        for (int sx = 0; sx < 2; ++sx) {
            aT[sy][sx] = *(const f2*)(plane + offT[sy][sx]);
            aB[sy][sx] = *(const f2*)(plane + offB[sy][sx]);
        }
        float acc = 0.0f;
#pragma unroll
        for (int sy = 0; sy < 2; ++sy)
#pragma unroll
        for (int sx = 0; sx < 2; ++sx) {
            acc += w00[sy][sx] * aT[sy][sx].x + w01[sy][sx] * aT[sy][sx].y
                 + w10[sy][sx] * aB[sy][sx].x + w11[sy][sx] * aB[sy][sx].y;
        }
        if (lane < NPP) out[ob] = acc;
        plane += LL;            // next channel plane (scalar bump)
        ob += NPP;
    }
}

extern "C" void kernel_launch(void* const* d_in, const int* in_sizes, int n_in,
                              void* d_out, int out_size, void* d_ws, size_t ws_size,
                              hipStream_t stream) {
    const float* boxes     = (const float*)d_in[0];
    const int*   batch_ids = (const int*)d_in[1];
    const float* g0        = (const float*)d_in[2];
    const float* g1        = (const float*)d_in[3];
    const float* g2        = (const float*)d_in[4];
    const float* g3        = (const float*)d_in[5];
    float* out = (float*)d_out;

    const int N = in_sizes[0] / 4;             // 512
    dim3 block(64, 4);                         // 4 waves; wave = 16-channel chunk
    dim3 grid(N, 4);                           // (512, 4): 16 chunks per box
    pooler_kernel<<<grid, block, 0, stream>>>(boxes, batch_ids, g0, g1, g2, g3, out);
}